// Round 11
// baseline (48.008 us; speedup 1.0000x reference)
//
#include <hip/hip_runtime.h>

// Deformable depthwise conv1d (fp32), MI355X.
// Round 11: NO LDS. R10's stencil reformulation left LDS used only for
// sequential window reads (L1-resident from global) and the never-taken
// fallback (now gathers from global with validity masks). Dropping LDS
// removes: 16.5KB/block occupancy cap (32% -> high), the staging pass +
// __syncthreads, and 4.87M bank-conflict cycles. Window edge cases are
// handled by clamped 16B-aligned bases + whole-quad zeroing in the
// (compile-time) first/last iterations only.
//   s_k = x[t+k] + a*(x[t+k-1]-x[t+k]) - c*(x[t+k+1]-x[t+k]),
//   a = max(-o,0), c = max(o,0)   (exact for |o| <= 1; zero-halo exact at edges)

constexpr int B_ = 8;
constexpr int C_ = 512;
constexpr int T_ = 4096;
constexpr int K_ = 7;
constexpr int T_OUT = T_ - K_ + 1;      // 4090
constexpr int BLOCK = 256;
constexpr int NOUT = 4;                 // consecutive outputs per thread
constexpr int SPAN = NOUT * BLOCK;      // 1024 t per iter
constexpr int NIT = 4;

__global__ __launch_bounds__(BLOCK)
void deform_dwconv1d_kernel(const float* __restrict__ x,
                            const float* __restrict__ weight,
                            const float* __restrict__ offset_w,
                            const float* __restrict__ offset_b,
                            float* __restrict__ out)
{
    const int bc  = blockIdx.x;        // b*C + c
    const int c   = bc & (C_ - 1);
    const int tid = threadIdx.x;

    const float* xrow = x + (size_t)bc * T_;

    // per-channel weights: uniform indices -> scalar (SGPR) loads
    float ow[K_ * K_];
    #pragma unroll
    for (int i = 0; i < K_ * K_; ++i) ow[i] = offset_w[c * K_ * K_ + i];
    float wgt[K_], ob[K_];
    #pragma unroll
    for (int k = 0; k < K_; ++k) {
        wgt[k] = weight[c * K_ + k];
        ob[k]  = offset_b[c * K_ + k];
    }

    float* orow = out + (size_t)bc * T_OUT;

    #pragma unroll
    for (int it = 0; it < NIT; ++it) {
        const int t0 = it * SPAN + tid * NOUT;   // multiple of 4, max 4092

        // ---- window x[t0-4 .. t0+11] via 4 coalesced float4 global loads.
        // All bases are multiples of 4 floats (16B-aligned). Edge quads are
        // either fully valid or fully out-of-range (stride-4 grid), so OOB
        // handling is clamp-base + zero-whole-quad, in it==0 / it==NIT-1 only.
        float4 F0, F1, F2, F3;
        if (it == 0) {
            F0 = *reinterpret_cast<const float4*>(xrow + max(t0 - 4, 0));
            if (t0 == 0) F0 = make_float4(0.f, 0.f, 0.f, 0.f);
        } else {
            F0 = *reinterpret_cast<const float4*>(xrow + t0 - 4);
        }
        F1 = *reinterpret_cast<const float4*>(xrow + t0);
        if (it == NIT - 1) {
            F2 = *reinterpret_cast<const float4*>(xrow + min(t0 + 4, T_ - 4));
            F3 = *reinterpret_cast<const float4*>(xrow + min(t0 + 8, T_ - 4));
            if (t0 + 4 > T_ - 4) F2 = make_float4(0.f, 0.f, 0.f, 0.f);
            if (t0 + 8 > T_ - 4) F3 = make_float4(0.f, 0.f, 0.f, 0.f);
        } else {
            F2 = *reinterpret_cast<const float4*>(xrow + t0 + 4);
            F3 = *reinterpret_cast<const float4*>(xrow + t0 + 8);
        }
        const float Wf[16] = {F0.x, F0.y, F0.z, F0.w,  F1.x, F1.y, F1.z, F1.w,
                              F2.x, F2.y, F2.z, F2.w,  F3.x, F3.y, F3.z, F3.w};
        // Wf[m] = x[t0-4+m] (zero outside [0,T-1])

        // shared differences: E[m] = Wf[m] - Wf[m+1]
        float E[14];
        #pragma unroll
        for (int m = 3; m < 14; ++m) E[m] = Wf[m] - Wf[m + 1];

        float acc[NOUT];
        float badm = 0.0f;                 // max |offs| over taps & outputs

        #pragma unroll
        for (int r = 0; r < NOUT; ++r) {
            float a2 = 0.0f;
            #pragma unroll
            for (int k = 0; k < K_; ++k) {
                // offset conv: o = bias + sum_j x[t+j]*ow[k][j], t = t0+r
                float o = ob[k];
                #pragma unroll
                for (int j = 0; j < K_; ++j)
                    o = fmaf(Wf[4 + r + j], ow[k * K_ + j], o);

                badm = fmaxf(badm, fabsf(o));   // v_max with |.| modifier

                // branchless 3-tap stencil, exact for |o| <= 1
                const float an = fmaxf(-o, 0.0f);
                const float cn = fmaxf(o, 0.0f);
                float s = fmaf(an, E[3 + r + k], Wf[4 + r + k]);
                s = fmaf(cn, -E[4 + r + k], s);
                a2 = fmaf(wgt[k], s, a2);
            }
            acc[r] = a2;
        }

        // exact fallback (wave-uniform, ~never taken): any |offs| > 1 ->
        // redo all 4 outputs via validity-masked global gathers (reference
        // semantics: zero outside [0, T-1], clip indices for the load).
        if (__any(badm > 1.0f)) {
            #pragma unroll
            for (int r = 0; r < NOUT; ++r) {
                float a2 = 0.0f;
                #pragma unroll
                for (int k = 0; k < K_; ++k) {
                    float o = ob[k];
                    #pragma unroll
                    for (int j = 0; j < K_; ++j)
                        o = fmaf(Wf[4 + r + j], ow[k * K_ + j], o);
                    const float pos = (float)(t0 + r + k) + o;
                    const float f   = floorf(pos);
                    const int   i0  = (int)f;
                    const float u   = pos - f;
                    const int c0 = min(max(i0, 0), T_ - 1);
                    const int c1 = min(max(i0 + 1, 0), T_ - 1);
                    float g0 = xrow[c0];
                    float g1 = xrow[c1];
                    if (i0 < 0 || i0 > T_ - 1) g0 = 0.0f;
                    if (i0 + 1 < 0 || i0 + 1 > T_ - 1) g1 = 0.0f;
                    a2 = fmaf(fmaf(u, g1 - g0, g0), wgt[k], a2);
                }
                acc[r] = a2;
            }
        }

        // stores: two 8B-aligned float2 per thread; guards only in the tail
        if (it < NIT - 1) {
            *reinterpret_cast<float2*>(orow + t0)     = make_float2(acc[0], acc[1]);
            *reinterpret_cast<float2*>(orow + t0 + 2) = make_float2(acc[2], acc[3]);
        } else {
            if (t0 + 1 < T_OUT)
                *reinterpret_cast<float2*>(orow + t0)     = make_float2(acc[0], acc[1]);
            if (t0 + 3 < T_OUT)
                *reinterpret_cast<float2*>(orow + t0 + 2) = make_float2(acc[2], acc[3]);
        }
    }
}

extern "C" void kernel_launch(void* const* d_in, const int* in_sizes, int n_in,
                              void* d_out, int out_size, void* d_ws, size_t ws_size,
                              hipStream_t stream) {
    const float* x        = (const float*)d_in[0];
    const float* weight   = (const float*)d_in[1];
    const float* offset_w = (const float*)d_in[2];
    const float* offset_b = (const float*)d_in[3];
    float* out = (float*)d_out;

    deform_dwconv1d_kernel<<<B_ * C_, BLOCK, 0, stream>>>(
        x, weight, offset_w, offset_b, out);
}